// Round 3
// baseline (7080.974 us; speedup 1.0000x reference)
//
#include <hip/hip_runtime.h>
#include <hip/hip_bf16.h>
#include <math.h>

#define TS   256
#define CTS  512
#define MB   64
#define D    512
#define KMIX 20

// d_out layout (floats): hiddens [TS][MB][D], att_k [TS][MB][KMIX], att_w [TS][MB][D]
#define HID_SIZE  (TS*MB*D)
#define ATTK_OFF  (HID_SIZE)
#define ATTW_OFF  (HID_SIZE + TS*MB*KMIX)

// ws layout (bytes):
#define WS_WRPK  0
#define WS_UPK   524288
#define WS_ALPHA 1048576
#define WS_BETA  2359296
#define WS_KINC  3670016
#define WS_X     5242880
#define WS_F2    38797312

typedef __attribute__((ext_vector_type(8))) short bf16x8;
typedef __attribute__((ext_vector_type(4))) float f32x4;

__device__ __forceinline__ unsigned short f2bf(float v) {
  __hip_bfloat16 h = __float2bfloat16(v);
  union { __hip_bfloat16 h; unsigned short u; } cvt; cvt.h = h;
  return cvt.u;
}

// ---------------- K0: pack recurrence weights into MFMA B-fragment order ----------------
// Fragment f = nt*16 + kt. Element (f, lane l, e): k = kt*32 + (l>>4)*8 + e ; n = nt*16 + (l&15).
__global__ __launch_bounds__(256) void pack_weights(const float* __restrict__ Wur,
                                                    const float* __restrict__ U,
                                                    unsigned short* __restrict__ WrPK,
                                                    unsigned short* __restrict__ UPK) {
  int idx = blockIdx.x * 256 + threadIdx.x;    // 512*512 = 262144 total
  int l = idx & 63;
  int e = (idx >> 6) & 7;
  int f = idx >> 9;
  int kt = f & 15, nt = f >> 4;
  int k = kt * 32 + ((l >> 4) << 3) + e;
  int n = (nt << 4) + (l & 15);
  int o = ((f * 64 + l) << 3) + e;
  WrPK[o] = f2bf(Wur[k * 1024 + 512 + n]);
  UPK[o]  = f2bf(U[k * 512 + n]);
}

// ---------------- K1: alpha = inp@Wa+ba (log domain), beta, kinc ----------------
#define ABK_ROWS 8
__global__ __launch_bounds__(64) void abk_kernel(const float* __restrict__ inp,
                                                 const float* __restrict__ Wa, const float* __restrict__ ba,
                                                 const float* __restrict__ Wb, const float* __restrict__ bb_,
                                                 const float* __restrict__ Wk, const float* __restrict__ bk,
                                                 float* __restrict__ alpha, float* __restrict__ beta,
                                                 float* __restrict__ kinc) {
  __shared__ float rows[ABK_ROWS][D];
  int tb0 = blockIdx.x * ABK_ROWS;
  for (int x = threadIdx.x; x < ABK_ROWS * D; x += 64)
    rows[x >> 9][x & 511] = inp[(size_t)tb0 * D + x];
  __syncthreads();
  int j = threadIdx.x;
  if (j >= 3 * KMIX) return;
  int wj = j % KMIX;
  int which = j / KMIX;
  const float* W = (which == 0) ? Wa : ((which == 1) ? Wb : Wk);
  const float* B = (which == 0) ? ba : ((which == 1) ? bb_ : bk);
  float acc[ABK_ROWS];
  float bias = B[wj];
#pragma unroll
  for (int r = 0; r < ABK_ROWS; r++) acc[r] = bias;
  for (int i = 0; i < D; i++) {
    float wv = W[i * KMIX + wj];
#pragma unroll
    for (int r = 0; r < ABK_ROWS; r++) acc[r] += rows[r][i] * wv;
  }
  for (int r = 0; r < ABK_ROWS; r++) {
    int tb = tb0 + r;
    float v = acc[r];
    if (which == 0) alpha[tb * KMIX + wj] = v;
    else if (which == 1) beta[tb * KMIX + wj] = expf(v);
    else kinc[tb * KMIX + wj] = expf(v);
  }
}

// ---------------- K2: k cumsum over t; writes att_k region of d_out ----------------
__global__ __launch_bounds__(256) void cumsum_kernel(const float* __restrict__ att_init,
                                                     const float* __restrict__ kinc,
                                                     float* __restrict__ kout) {
  int idx = blockIdx.x * 256 + threadIdx.x;
  if (idx >= MB * KMIX) return;
  float k = att_init[idx];
  for (int t = 0; t < TS; t++) {
    k += kinc[t * MB * KMIX + idx];
    kout[t * MB * KMIX + idx] = k;
  }
}

// ---------------- K3: phi + w GEMM; writes att_w region of d_out ----------------
#define WT 8
__global__ __launch_bounds__(512) void phi_w_kernel(const float* __restrict__ c_inp,
                                                    const float* __restrict__ alpha,
                                                    const float* __restrict__ beta,
                                                    const float* __restrict__ katt,
                                                    float* __restrict__ wout) {
  int b  = blockIdx.x / (TS / WT);
  int t0 = (blockIdx.x % (TS / WT)) * WT;
  __shared__ float phi[WT][CTS];
  __shared__ float pa[WT][KMIX], pb[WT][KMIX], pk[WT][KMIX];
  for (int x = threadIdx.x; x < WT * KMIX; x += 512) {
    int tt = x / KMIX, j = x % KMIX;
    int tb = (t0 + tt) * MB + b;
    pa[tt][j] = alpha[tb * KMIX + j];
    pb[tt][j] = beta[tb * KMIX + j];
    pk[tt][j] = katt[tb * KMIX + j];
  }
  __syncthreads();
  {
    int c = threadIdx.x;
    float fc = (float)c;
#pragma unroll
    for (int tt = 0; tt < WT; tt++) {
      float s = 0.f;
#pragma unroll
      for (int j = 0; j < KMIX; j++) {
        float dd = pk[tt][j] - fc;
        s += expf(pa[tt][j] - pb[tt][j] * dd * dd);
      }
      phi[tt][c] = s;
    }
  }
  __syncthreads();
  {
    int d = threadIdx.x;
    float acc[WT];
#pragma unroll
    for (int tt = 0; tt < WT; tt++) acc[tt] = 0.f;
    const float* cb = c_inp + (size_t)b * D + d;
    for (int c2 = 0; c2 < CTS; c2++) {
      float cv = cb[(size_t)c2 * (MB * D)];
#pragma unroll
      for (int tt = 0; tt < WT; tt++) acc[tt] += phi[tt][c2] * cv;
    }
    for (int tt = 0; tt < WT; tt++)
      wout[((size_t)(t0 + tt) * MB + b) * D + d] = acc[tt];
  }
}

// ---------------- K4/K5: fp32 tiled GEMM, 128x128 tile ----------------
__global__ __launch_bounds__(256) void gemm128(const float* __restrict__ A,
                                               const float* __restrict__ B,
                                               const float* __restrict__ bias,
                                               const float* __restrict__ wadd,
                                               float* __restrict__ C,
                                               int Kdim, int ldb, int Nout, int remapHalf) {
  __shared__ float As[8][128];
  __shared__ float Bs[8][128];
  const int bm = blockIdx.x, bn = blockIdx.y;
  const int tid = threadIdx.x;
  const int tm = (tid >> 4) << 3;
  const int tn = (tid & 15) << 3;
  const int colOff = (remapHalf && bn >= 4) ? 512 : 0;
  const int n0 = bn * 128;
  float acc[8][8];
#pragma unroll
  for (int i = 0; i < 8; i++)
#pragma unroll
    for (int j = 0; j < 8; j++) acc[i][j] = 0.f;
  const int ar = tid >> 1;
  const int ak = (tid & 1) << 2;
  const int bkr = tid >> 5;
  const int bc = (tid & 31) << 2;
  const float* Aptr = A + (size_t)(bm * 128 + ar) * Kdim + ak;
  const float* Bptr = B + (size_t)bkr * ldb + n0 + colOff + bc;
  for (int k0 = 0; k0 < Kdim; k0 += 8) {
    float4 a4 = *(const float4*)(Aptr + k0);
    float4 b4 = *(const float4*)(Bptr + (size_t)k0 * ldb);
    As[ak + 0][ar] = a4.x; As[ak + 1][ar] = a4.y; As[ak + 2][ar] = a4.z; As[ak + 3][ar] = a4.w;
    *(float4*)&Bs[bkr][bc] = b4;
    __syncthreads();
#pragma unroll
    for (int kk = 0; kk < 8; kk++) {
      float a8[8], b8[8];
      *(float4*)&a8[0] = *(const float4*)&As[kk][tm];
      *(float4*)&a8[4] = *(const float4*)&As[kk][tm + 4];
      *(float4*)&b8[0] = *(const float4*)&Bs[kk][tn];
      *(float4*)&b8[4] = *(const float4*)&Bs[kk][tn + 4];
#pragma unroll
      for (int i = 0; i < 8; i++)
#pragma unroll
        for (int j = 0; j < 8; j++) acc[i][j] += a8[i] * b8[j];
    }
    __syncthreads();
  }
  float bb8[8];
#pragma unroll
  for (int j = 0; j < 8; j++) bb8[j] = bias[n0 + colOff + tn + j];
#pragma unroll
  for (int i = 0; i < 8; i++) {
    int m = bm * 128 + tm + i;
    size_t co = (size_t)m * Nout + n0 + tn;
    float v[8];
#pragma unroll
    for (int j = 0; j < 8; j++) v[j] = acc[i][j] + bb8[j];
    if (wadd) {
      float4 w0 = *(const float4*)&wadd[co];
      float4 w1 = *(const float4*)&wadd[co + 4];
      v[0] += w0.x; v[1] += w0.y; v[2] += w0.z; v[3] += w0.w;
      v[4] += w1.x; v[5] += w1.y; v[6] += w1.z; v[7] += w1.w;
    }
    *(float4*)&C[co]     = make_float4(v[0], v[1], v[2], v[3]);
    *(float4*)&C[co + 4] = make_float4(v[4], v[5], v[6], v[7]);
  }
}

// ---------------- K6: MFMA recurrence, weights resident in VGPR/AGPR ----------------
// 4 blocks x 1024 threads (16 waves). Block handles 16 batches; wave owns 2 n-tiles (32 cols).
// Weight slices (bf16x8 frags) preloaded to registers once: 256 VGPRs/thread.
// h / sr staged in LDS in A-fragment order with chunk XOR swizzle (conflict-free b128 reads,
// ~2-way b16 writes).  Frag store: value (m, j) -> kt=j>>5, chunk L=((j>>3)&3)<<4|m,
// swizzled Ls = L ^ ((L>>3)&7), elem j&7.

__device__ __forceinline__ int st_off(int m, int j) {
  int L = (((j >> 3) & 3) << 4) | m;
  int Ls = L ^ ((L >> 3) & 7);
  return ((j >> 5) << 10) + (Ls << 3) + (j & 7);
}

__device__ __forceinline__ float fast_sigmoid(float x) {
  return __builtin_amdgcn_rcpf(1.f + __expf(-x));
}
__device__ __forceinline__ float fast_tanh(float x) {
  x = fminf(15.f, fmaxf(-15.f, x));
  float e = __expf(2.f * x);
  return 1.f - 2.f * __builtin_amdgcn_rcpf(e + 1.f);
}

__global__ __launch_bounds__(1024) void recurrence_mfma(
    const float* __restrict__ F2,
    const bf16x8* __restrict__ WrPK,
    const bf16x8* __restrict__ UPK,
    const float* __restrict__ gru_init,
    float* __restrict__ hout) {
  __shared__ unsigned short hbf[16 * 1024];
  __shared__ unsigned short srbf[16 * 1024];
  const int tid  = threadIdx.x;
  const int wave = tid >> 6;        // 0..15
  const int lane = tid & 63;
  const int lg = lane >> 4;
  const int ln = lane & 15;
  const int b0 = blockIdx.x * 16;
  const int Lsrd = lane ^ ((lane >> 3) & 7);   // read chunk for A-frags

  // ---- preload weight slices into registers (static indices, fully unrolled) ----
  bf16x8 wrw[2][16], uw[2][16];
#pragma unroll
  for (int q = 0; q < 2; q++)
#pragma unroll
    for (int kt = 0; kt < 16; kt++) {
      int f = ((wave * 2 + q) * 16 + kt);
      wrw[q][kt] = WrPK[(f << 6) + lane];
      uw[q][kt]  = UPK[(f << 6) + lane];
    }

  // ---- init h ----
  float hreg[2][4];
#pragma unroll
  for (int q = 0; q < 2; q++) {
    int j = ((wave * 2 + q) << 4) + ln;
#pragma unroll
    for (int r = 0; r < 4; r++) {
      int m = (lg << 2) + r;
      float v = gru_init[(b0 + m) * D + j];
      hreg[q][r] = v;
      hbf[st_off(m, j)] = f2bf(v);
    }
  }
  __syncthreads();

  // ---- preload F2 for t=0 ----
  float sreg[2][4], greg[2][4];
  {
    const float* f2 = F2 + (size_t)b0 * 1024;
#pragma unroll
    for (int q = 0; q < 2; q++) {
      int j = ((wave * 2 + q) << 4) + ln;
#pragma unroll
      for (int r = 0; r < 4; r++) {
        int m = (lg << 2) + r;
        sreg[q][r] = f2[m * 1024 + j];
        greg[q][r] = f2[m * 1024 + 512 + j];
      }
    }
  }

  const f32x4 zero4 = {0.f, 0.f, 0.f, 0.f};
#pragma unroll 1
  for (int t = 0; t < TS; t++) {
    // prefetch F2 for t+1
    float nsreg[2][4], ngreg[2][4];
    {
      int tn_ = (t + 1 < TS) ? (t + 1) : t;
      const float* f2n = F2 + ((size_t)tn_ * MB + b0) * 1024;
#pragma unroll
      for (int q = 0; q < 2; q++) {
        int j = ((wave * 2 + q) << 4) + ln;
#pragma unroll
        for (int r = 0; r < 4; r++) {
          int m = (lg << 2) + r;
          nsreg[q][r] = f2n[m * 1024 + j];
          ngreg[q][r] = f2n[m * 1024 + 512 + j];
        }
      }
    }
    // ---- matvec 1: h @ Wr ----
    f32x4 c1[2] = {zero4, zero4};
#pragma unroll
    for (int kt = 0; kt < 16; kt++) {
      bf16x8 a = *(const bf16x8*)(hbf + (kt << 10) + (Lsrd << 3));
      c1[0] = __builtin_amdgcn_mfma_f32_16x16x32_bf16(a, wrw[0][kt], c1[0], 0, 0, 0);
      c1[1] = __builtin_amdgcn_mfma_f32_16x16x32_bf16(a, wrw[1][kt], c1[1], 0, 0, 0);
    }
    // ---- epilogue 1: sr = s * sigmoid(c1 + g) ----
#pragma unroll
    for (int q = 0; q < 2; q++) {
      int j = ((wave * 2 + q) << 4) + ln;
#pragma unroll
      for (int r = 0; r < 4; r++) {
        int m = (lg << 2) + r;
        float rr = fast_sigmoid(c1[q][r] + greg[q][r]);
        srbf[st_off(m, j)] = f2bf(sreg[q][r] * rr);
      }
    }
    __syncthreads();
    // ---- matvec 2: sr @ U ----
    f32x4 c2[2] = {zero4, zero4};
#pragma unroll
    for (int kt = 0; kt < 16; kt++) {
      bf16x8 a = *(const bf16x8*)(srbf + (kt << 10) + (Lsrd << 3));
      c2[0] = __builtin_amdgcn_mfma_f32_16x16x32_bf16(a, uw[0][kt], c2[0], 0, 0, 0);
      c2[1] = __builtin_amdgcn_mfma_f32_16x16x32_bf16(a, uw[1][kt], c2[1], 0, 0, 0);
    }
    // ---- epilogue 2: h += 1 + tanh(c2 + s) ----
#pragma unroll
    for (int q = 0; q < 2; q++) {
      int j = ((wave * 2 + q) << 4) + ln;
#pragma unroll
      for (int r = 0; r < 4; r++) {
        int m = (lg << 2) + r;
        float hn = hreg[q][r] + 1.f + fast_tanh(c2[q][r] + sreg[q][r]);
        hreg[q][r] = hn;
        hout[((size_t)t * MB + (b0 + m)) * D + j] = hn;
        hbf[st_off(m, j)] = f2bf(hn);
      }
    }
    __syncthreads();
#pragma unroll
    for (int q = 0; q < 2; q++)
#pragma unroll
      for (int r = 0; r < 4; r++) {
        sreg[q][r] = nsreg[q][r];
        greg[q][r] = ngreg[q][r];
      }
  }
}

extern "C" void kernel_launch(void* const* d_in, const int* in_sizes, int n_in,
                              void* d_out, int out_size, void* d_ws, size_t ws_size,
                              hipStream_t stream) {
  const float* c_inp    = (const float*)d_in[0];
  const float* inp      = (const float*)d_in[1];
  const float* gru_init = (const float*)d_in[2];
  const float* att_init = (const float*)d_in[3];
  const float* Wa   = (const float*)d_in[4];
  const float* ba   = (const float*)d_in[5];
  const float* Wb   = (const float*)d_in[6];
  const float* bb   = (const float*)d_in[7];
  const float* Wk   = (const float*)d_in[8];
  const float* bk   = (const float*)d_in[9];
  const float* Wif  = (const float*)d_in[10];
  const float* bif  = (const float*)d_in[11];
  const float* Wfork= (const float*)d_in[12];
  const float* bfork= (const float*)d_in[13];
  const float* Wur  = (const float*)d_in[14];
  const float* U    = (const float*)d_in[15];

  float* out = (float*)d_out;
  float* hid  = out;
  float* attk = out + ATTK_OFF;
  float* attw = out + ATTW_OFF;

  char* ws = (char*)d_ws;
  unsigned short* WrPK = (unsigned short*)(ws + WS_WRPK);
  unsigned short* UPK  = (unsigned short*)(ws + WS_UPK);
  float* alpha = (float*)(ws + WS_ALPHA);
  float* beta  = (float*)(ws + WS_BETA);
  float* kinc  = (float*)(ws + WS_KINC);
  float* X     = (float*)(ws + WS_X);
  float* F2    = (float*)(ws + WS_F2);

  hipLaunchKernelGGL(pack_weights, dim3(1024), dim3(256), 0, stream, Wur, U, WrPK, UPK);
  hipLaunchKernelGGL(abk_kernel, dim3(TS * MB / ABK_ROWS), dim3(64), 0, stream,
                     inp, Wa, ba, Wb, bb, Wk, bk, alpha, beta, kinc);
  hipLaunchKernelGGL(cumsum_kernel, dim3((MB * KMIX + 255) / 256), dim3(256), 0, stream,
                     att_init, kinc, attk);
  hipLaunchKernelGGL(phi_w_kernel, dim3(MB * (TS / WT)), dim3(512), 0, stream,
                     c_inp, alpha, beta, attk, attw);
  hipLaunchKernelGGL(gemm128, dim3(TS * MB / 128, D / 128), dim3(256), 0, stream,
                     inp, Wif, bif, attw, X, D, D, D, 0);
  hipLaunchKernelGGL(gemm128, dim3(TS * MB / 128, 1024 / 128), dim3(256), 0, stream,
                     X, Wfork, bfork, (const float*)nullptr, F2, D, 3 * D, 1024, 1);
  hipLaunchKernelGGL(recurrence_mfma, dim3(4), dim3(1024), 0, stream,
                     F2, (const bf16x8*)WrPK, (const bf16x8*)UPK, gru_init, hid);
}

// Round 5
// 6753.568 us; speedup vs baseline: 1.0485x; 1.0485x over previous
//
#include <hip/hip_runtime.h>
#include <hip/hip_bf16.h>
#include <math.h>

#define TS   256
#define CTS  512
#define MB   64
#define D    512
#define KMIX 20

// d_out layout (floats): hiddens [TS][MB][D], att_k [TS][MB][KMIX], att_w [TS][MB][D]
#define HID_SIZE  (TS*MB*D)
#define ATTK_OFF  (HID_SIZE)
#define ATTW_OFF  (HID_SIZE + TS*MB*KMIX)

// ws layout (bytes):
#define WS_WRPK  0
#define WS_UPK   524288
#define WS_ALPHA 1048576
#define WS_BETA  2359296
#define WS_KINC  3670016
#define WS_X     5242880
#define WS_F2    38797312

typedef __attribute__((ext_vector_type(8))) short bf16x8;
typedef __attribute__((ext_vector_type(4))) float f32x4;

__device__ __forceinline__ unsigned short f2bf(float v) {
  __hip_bfloat16 h = __float2bfloat16(v);
  union { __hip_bfloat16 h; unsigned short u; } cvt; cvt.h = h;
  return cvt.u;
}

// ---------------- K0: pack recurrence weights into MFMA B-fragment order ----------------
// Fragment f = nt*16 + kt. Element (f, lane l, e): k = kt*32 + (l>>4)*8 + e ; n = nt*16 + (l&15).
__global__ __launch_bounds__(256) void pack_weights(const float* __restrict__ Wur,
                                                    const float* __restrict__ U,
                                                    unsigned short* __restrict__ WrPK,
                                                    unsigned short* __restrict__ UPK) {
  int idx = blockIdx.x * 256 + threadIdx.x;    // 512*512 = 262144 total
  int l = idx & 63;
  int e = (idx >> 6) & 7;
  int f = idx >> 9;
  int kt = f & 15, nt = f >> 4;
  int k = kt * 32 + ((l >> 4) << 3) + e;
  int n = (nt << 4) + (l & 15);
  int o = ((f * 64 + l) << 3) + e;
  WrPK[o] = f2bf(Wur[k * 1024 + 512 + n]);
  UPK[o]  = f2bf(U[k * 512 + n]);
}

// ---------------- K1: alpha = inp@Wa+ba (log domain), beta, kinc ----------------
#define ABK_ROWS 8
__global__ __launch_bounds__(64) void abk_kernel(const float* __restrict__ inp,
                                                 const float* __restrict__ Wa, const float* __restrict__ ba,
                                                 const float* __restrict__ Wb, const float* __restrict__ bb_,
                                                 const float* __restrict__ Wk, const float* __restrict__ bk,
                                                 float* __restrict__ alpha, float* __restrict__ beta,
                                                 float* __restrict__ kinc) {
  __shared__ float rows[ABK_ROWS][D];
  int tb0 = blockIdx.x * ABK_ROWS;
  for (int x = threadIdx.x; x < ABK_ROWS * D; x += 64)
    rows[x >> 9][x & 511] = inp[(size_t)tb0 * D + x];
  __syncthreads();
  int j = threadIdx.x;
  if (j >= 3 * KMIX) return;
  int wj = j % KMIX;
  int which = j / KMIX;
  const float* W = (which == 0) ? Wa : ((which == 1) ? Wb : Wk);
  const float* B = (which == 0) ? ba : ((which == 1) ? bb_ : bk);
  float acc[ABK_ROWS];
  float bias = B[wj];
#pragma unroll
  for (int r = 0; r < ABK_ROWS; r++) acc[r] = bias;
  for (int i = 0; i < D; i++) {
    float wv = W[i * KMIX + wj];
#pragma unroll
    for (int r = 0; r < ABK_ROWS; r++) acc[r] += rows[r][i] * wv;
  }
  for (int r = 0; r < ABK_ROWS; r++) {
    int tb = tb0 + r;
    float v = acc[r];
    if (which == 0) alpha[tb * KMIX + wj] = v;
    else if (which == 1) beta[tb * KMIX + wj] = expf(v);
    else kinc[tb * KMIX + wj] = expf(v);
  }
}

// ---------------- K2: k cumsum over t; writes att_k region of d_out ----------------
__global__ __launch_bounds__(256) void cumsum_kernel(const float* __restrict__ att_init,
                                                     const float* __restrict__ kinc,
                                                     float* __restrict__ kout) {
  int idx = blockIdx.x * 256 + threadIdx.x;
  if (idx >= MB * KMIX) return;
  float k = att_init[idx];
  for (int t = 0; t < TS; t++) {
    k += kinc[t * MB * KMIX + idx];
    kout[t * MB * KMIX + idx] = k;
  }
}

// ---------------- K3: phi + w GEMM; writes att_w region of d_out ----------------
#define WT 16
__global__ __launch_bounds__(512) void phi_w_kernel(const float* __restrict__ c_inp,
                                                    const float* __restrict__ alpha,
                                                    const float* __restrict__ beta,
                                                    const float* __restrict__ katt,
                                                    float* __restrict__ wout) {
  int b  = blockIdx.x / (TS / WT);
  int t0 = (blockIdx.x % (TS / WT)) * WT;
  __shared__ float phi[WT][CTS];
  __shared__ float pa[WT][KMIX], pb[WT][KMIX], pk[WT][KMIX];
  for (int x = threadIdx.x; x < WT * KMIX; x += 512) {
    int tt = x / KMIX, j = x % KMIX;
    int tb = (t0 + tt) * MB + b;
    pa[tt][j] = alpha[tb * KMIX + j];
    pb[tt][j] = beta[tb * KMIX + j];
    pk[tt][j] = katt[tb * KMIX + j];
  }
  __syncthreads();
  {
    int c = threadIdx.x;
    float fc = (float)c;
#pragma unroll
    for (int tt = 0; tt < WT; tt++) {
      float s = 0.f;
#pragma unroll
      for (int j = 0; j < KMIX; j++) {
        float dd = pk[tt][j] - fc;
        s += expf(pa[tt][j] - pb[tt][j] * dd * dd);
      }
      phi[tt][c] = s;
    }
  }
  __syncthreads();
  {
    int d = threadIdx.x;
    float acc[WT];
#pragma unroll
    for (int tt = 0; tt < WT; tt++) acc[tt] = 0.f;
    const float* cb = c_inp + (size_t)b * D + d;
    for (int c2 = 0; c2 < CTS; c2++) {
      float cv = cb[(size_t)c2 * (MB * D)];
#pragma unroll
      for (int tt = 0; tt < WT; tt++) acc[tt] += phi[tt][c2] * cv;
    }
    for (int tt = 0; tt < WT; tt++)
      wout[((size_t)(t0 + tt) * MB + b) * D + d] = acc[tt];
  }
}

// ---------------- K4/K5: fp32 tiled GEMM, 128x128 tile ----------------
__global__ __launch_bounds__(256) void gemm128(const float* __restrict__ A,
                                               const float* __restrict__ B,
                                               const float* __restrict__ bias,
                                               const float* __restrict__ wadd,
                                               float* __restrict__ C,
                                               int Kdim, int ldb, int Nout, int remapHalf) {
  __shared__ float As[8][128];
  __shared__ float Bs[8][128];
  const int bm = blockIdx.x, bn = blockIdx.y;
  const int tid = threadIdx.x;
  const int tm = (tid >> 4) << 3;
  const int tn = (tid & 15) << 3;
  const int colOff = (remapHalf && bn >= 4) ? 512 : 0;
  const int n0 = bn * 128;
  float acc[8][8];
#pragma unroll
  for (int i = 0; i < 8; i++)
#pragma unroll
    for (int j = 0; j < 8; j++) acc[i][j] = 0.f;
  const int ar = tid >> 1;
  const int ak = (tid & 1) << 2;
  const int bkr = tid >> 5;
  const int bc = (tid & 31) << 2;
  const float* Aptr = A + (size_t)(bm * 128 + ar) * Kdim + ak;
  const float* Bptr = B + (size_t)bkr * ldb + n0 + colOff + bc;
  for (int k0 = 0; k0 < Kdim; k0 += 8) {
    float4 a4 = *(const float4*)(Aptr + k0);
    float4 b4 = *(const float4*)(Bptr + (size_t)k0 * ldb);
    As[ak + 0][ar] = a4.x; As[ak + 1][ar] = a4.y; As[ak + 2][ar] = a4.z; As[ak + 3][ar] = a4.w;
    *(float4*)&Bs[bkr][bc] = b4;
    __syncthreads();
#pragma unroll
    for (int kk = 0; kk < 8; kk++) {
      float a8[8], b8[8];
      *(float4*)&a8[0] = *(const float4*)&As[kk][tm];
      *(float4*)&a8[4] = *(const float4*)&As[kk][tm + 4];
      *(float4*)&b8[0] = *(const float4*)&Bs[kk][tn];
      *(float4*)&b8[4] = *(const float4*)&Bs[kk][tn + 4];
#pragma unroll
      for (int i = 0; i < 8; i++)
#pragma unroll
        for (int j = 0; j < 8; j++) acc[i][j] += a8[i] * b8[j];
    }
    __syncthreads();
  }
  float bb8[8];
#pragma unroll
  for (int j = 0; j < 8; j++) bb8[j] = bias[n0 + colOff + tn + j];
#pragma unroll
  for (int i = 0; i < 8; i++) {
    int m = bm * 128 + tm + i;
    size_t co = (size_t)m * Nout + n0 + tn;
    float v[8];
#pragma unroll
    for (int j = 0; j < 8; j++) v[j] = acc[i][j] + bb8[j];
    if (wadd) {
      float4 w0 = *(const float4*)&wadd[co];
      float4 w1 = *(const float4*)&wadd[co + 4];
      v[0] += w0.x; v[1] += w0.y; v[2] += w0.z; v[3] += w0.w;
      v[4] += w1.x; v[5] += w1.y; v[6] += w1.z; v[7] += w1.w;
    }
    *(float4*)&C[co]     = make_float4(v[0], v[1], v[2], v[3]);
    *(float4*)&C[co + 4] = make_float4(v[4], v[5], v[6], v[7]);
  }
}

// ---------------- K6: MFMA recurrence, weights streamed from L2 with 2-deep prefetch ----
// 4 blocks x 1024 threads (16 waves). Block: 16 batches; wave: 2 n-tiles (32 cols).
// h / sr staged in LDS in A-fragment order with chunk XOR swizzle (conflict-free, verified
// round 3: SQ_LDS_BANK_CONFLICT=0).  Per-wave live VGPRs ~100 (cap 128 at 1024 thr) — no
// resident weight arrays (round-3 lesson: RF is 512KB/CU; 1MB cannot be resident).

__device__ __forceinline__ int st_off(int m, int j) {
  int L = (((j >> 3) & 3) << 4) | m;
  int Ls = L ^ ((L >> 3) & 7);
  return ((j >> 5) << 10) + (Ls << 3) + (j & 7);
}

__device__ __forceinline__ float fast_sigmoid(float x) {
  return __builtin_amdgcn_rcpf(1.f + __expf(-x));
}
__device__ __forceinline__ float fast_tanh(float x) {
  x = fminf(15.f, fmaxf(-15.f, x));
  float e = __expf(2.f * x);
  return 1.f - 2.f * __builtin_amdgcn_rcpf(e + 1.f);
}

__global__ __launch_bounds__(1024) void recurrence_mfma(
    const float* __restrict__ F2,
    const bf16x8* __restrict__ WrPK,
    const bf16x8* __restrict__ UPK,
    const float* __restrict__ gru_init,
    float* __restrict__ hout) {
  __shared__ unsigned short hbf[16 * 1024];
  __shared__ unsigned short srbf[16 * 1024];
  const int tid  = threadIdx.x;
  const int wave = tid >> 6;        // 0..15
  const int lane = tid & 63;
  const int lg = lane >> 4;
  const int ln = lane & 15;
  const int b0 = blockIdx.x * 16;
  const int Lsrd = lane ^ ((lane >> 3) & 7);   // swizzled read chunk for A-frags

  // Per-wave fragment base pointers (lane folded in). frag f = nt*16+kt at WrPK[f*64+lane].
  const bf16x8* wr0 = WrPK + (((wave * 2 + 0) * 16) << 6) + lane;
  const bf16x8* wr1 = WrPK + (((wave * 2 + 1) * 16) << 6) + lane;
  const bf16x8* u0  = UPK  + (((wave * 2 + 0) * 16) << 6) + lane;
  const bf16x8* u1  = UPK  + (((wave * 2 + 1) * 16) << 6) + lane;

  // ---- init h ----
  float hreg[2][4];
#pragma unroll
  for (int q = 0; q < 2; q++) {
    int j = ((wave * 2 + q) << 4) + ln;
#pragma unroll
    for (int r = 0; r < 4; r++) {
      int m = (lg << 2) + r;
      float v = gru_init[(b0 + m) * D + j];
      hreg[q][r] = v;
      hbf[st_off(m, j)] = f2bf(v);
    }
  }
  __syncthreads();

  const f32x4 zero4 = {0.f, 0.f, 0.f, 0.f};
#pragma unroll 1
  for (int t = 0; t < TS; t++) {
    // issue s/g loads for this step (consumed after matvec1 — hidden under the stream)
    const float* f2 = F2 + ((size_t)t * MB + b0) * 1024;
    float sreg[2][4], greg[2][4];
#pragma unroll
    for (int q = 0; q < 2; q++) {
      int j = ((wave * 2 + q) << 4) + ln;
#pragma unroll
      for (int r = 0; r < 4; r++) {
        int m = (lg << 2) + r;
        sreg[q][r] = f2[m * 1024 + j];
        greg[q][r] = f2[m * 1024 + 512 + j];
      }
    }
    // ---- matvec 1: h @ Wr, 2-deep ping-pong prefetch ----
    f32x4 c1[2] = {zero4, zero4};
    {
      bf16x8 p0a = wr0[0 << 6], p0b = wr1[0 << 6];
      bf16x8 p1a = wr0[1 << 6], p1b = wr1[1 << 6];
#pragma unroll
      for (int kt = 0; kt < 16; kt++) {
        bf16x8 ca = p0a, cb = p0b;
        p0a = p1a; p0b = p1b;
        int ktn = (kt + 2 < 16) ? (kt + 2) : 15;
        p1a = wr0[ktn << 6];
        p1b = wr1[ktn << 6];
        bf16x8 a = *(const bf16x8*)(hbf + (kt << 10) + (Lsrd << 3));
        c1[0] = __builtin_amdgcn_mfma_f32_16x16x32_bf16(a, ca, c1[0], 0, 0, 0);
        c1[1] = __builtin_amdgcn_mfma_f32_16x16x32_bf16(a, cb, c1[1], 0, 0, 0);
      }
    }
    // ---- epilogue 1: sr = s * sigmoid(c1 + g) ----
#pragma unroll
    for (int q = 0; q < 2; q++) {
      int j = ((wave * 2 + q) << 4) + ln;
#pragma unroll
      for (int r = 0; r < 4; r++) {
        int m = (lg << 2) + r;
        float rr = fast_sigmoid(c1[q][r] + greg[q][r]);
        srbf[st_off(m, j)] = f2bf(sreg[q][r] * rr);
      }
    }
    __syncthreads();
    // ---- matvec 2: sr @ U, 2-deep ping-pong prefetch ----
    f32x4 c2[2] = {zero4, zero4};
    {
      bf16x8 p0a = u0[0 << 6], p0b = u1[0 << 6];
      bf16x8 p1a = u0[1 << 6], p1b = u1[1 << 6];
#pragma unroll
      for (int kt = 0; kt < 16; kt++) {
        bf16x8 ca = p0a, cb = p0b;
        p0a = p1a; p0b = p1b;
        int ktn = (kt + 2 < 16) ? (kt + 2) : 15;
        p1a = u0[ktn << 6];
        p1b = u1[ktn << 6];
        bf16x8 a = *(const bf16x8*)(srbf + (kt << 10) + (Lsrd << 3));
        c2[0] = __builtin_amdgcn_mfma_f32_16x16x32_bf16(a, ca, c2[0], 0, 0, 0);
        c2[1] = __builtin_amdgcn_mfma_f32_16x16x32_bf16(a, cb, c2[1], 0, 0, 0);
      }
    }
    // ---- epilogue 2: h += 1 + tanh(c2 + s) ----
#pragma unroll
    for (int q = 0; q < 2; q++) {
      int j = ((wave * 2 + q) << 4) + ln;
#pragma unroll
      for (int r = 0; r < 4; r++) {
        int m = (lg << 2) + r;
        float hn = hreg[q][r] + 1.f + fast_tanh(c2[q][r] + sreg[q][r]);
        hreg[q][r] = hn;
        hout[((size_t)t * MB + (b0 + m)) * D + j] = hn;
        hbf[st_off(m, j)] = f2bf(hn);
      }
    }
    __syncthreads();
  }
}

extern "C" void kernel_launch(void* const* d_in, const int* in_sizes, int n_in,
                              void* d_out, int out_size, void* d_ws, size_t ws_size,
                              hipStream_t stream) {
  const float* c_inp    = (const float*)d_in[0];
  const float* inp      = (const float*)d_in[1];
  const float* gru_init = (const float*)d_in[2];
  const float* att_init = (const float*)d_in[3];
  const float* Wa   = (const float*)d_in[4];
  const float* ba   = (const float*)d_in[5];
  const float* Wb   = (const float*)d_in[6];
  const float* bb   = (const float*)d_in[7];
  const float* Wk   = (const float*)d_in[8];
  const float* bk   = (const float*)d_in[9];
  const float* Wif  = (const float*)d_in[10];
  const float* bif  = (const float*)d_in[11];
  const float* Wfork= (const float*)d_in[12];
  const float* bfork= (const float*)d_in[13];
  const float* Wur  = (const float*)d_in[14];
  const float* U    = (const float*)d_in[15];

  float* out = (float*)d_out;
  float* hid  = out;
  float* attk = out + ATTK_OFF;
  float* attw = out + ATTW_OFF;

  char* ws = (char*)d_ws;
  unsigned short* WrPK = (unsigned short*)(ws + WS_WRPK);
  unsigned short* UPK  = (unsigned short*)(ws + WS_UPK);
  float* alpha = (float*)(ws + WS_ALPHA);
  float* beta  = (float*)(ws + WS_BETA);
  float* kinc  = (float*)(ws + WS_KINC);
  float* X     = (float*)(ws + WS_X);
  float* F2    = (float*)(ws + WS_F2);

  hipLaunchKernelGGL(pack_weights, dim3(1024), dim3(256), 0, stream, Wur, U, WrPK, UPK);
  hipLaunchKernelGGL(abk_kernel, dim3(TS * MB / ABK_ROWS), dim3(64), 0, stream,
                     inp, Wa, ba, Wb, bb, Wk, bk, alpha, beta, kinc);
  hipLaunchKernelGGL(cumsum_kernel, dim3((MB * KMIX + 255) / 256), dim3(256), 0, stream,
                     att_init, kinc, attk);
  hipLaunchKernelGGL(phi_w_kernel, dim3(MB * (TS / WT)), dim3(512), 0, stream,
                     c_inp, alpha, beta, attk, attw);
  hipLaunchKernelGGL(gemm128, dim3(TS * MB / 128, D / 128), dim3(256), 0, stream,
                     inp, Wif, bif, attw, X, D, D, D, 0);
  hipLaunchKernelGGL(gemm128, dim3(TS * MB / 128, 1024 / 128), dim3(256), 0, stream,
                     X, Wfork, bfork, (const float*)nullptr, F2, D, 3 * D, 1024, 1);
  hipLaunchKernelGGL(recurrence_mfma, dim3(4), dim3(1024), 0, stream,
                     F2, (const bf16x8*)WrPK, (const bf16x8*)UPK, gru_init, hid);
}

// Round 6
// 5997.073 us; speedup vs baseline: 1.1807x; 1.1261x over previous
//
#include <hip/hip_runtime.h>
#include <hip/hip_bf16.h>
#include <math.h>

#define TS   256
#define CTS  512
#define MB   64
#define D    512
#define KMIX 20

// d_out layout (floats): hiddens [TS][MB][D], att_k [TS][MB][KMIX], att_w [TS][MB][D]
#define HID_SIZE  (TS*MB*D)
#define ATTK_OFF  (HID_SIZE)
#define ATTW_OFF  (HID_SIZE + TS*MB*KMIX)

// ws layout (bytes):
#define WS_WRPK  0
#define WS_UPK   524288
#define WS_ALPHA 1048576
#define WS_BETA  2359296
#define WS_KINC  3670016
// gap 4980736..5242880 reused for barrier + exchange buffers:
#define WS_BAR   4980736      // 4KB (512 u32 counters used)
#define WS_SRX   4984832      // 64KB bf16 sr exchange (frag layout)
#define WS_HX    5050368      // 64KB bf16 h  exchange (frag layout)
#define WS_X     5242880
#define WS_F2    38797312

typedef __attribute__((ext_vector_type(8))) short bf16x8;
typedef __attribute__((ext_vector_type(4))) float f32x4;

__device__ __forceinline__ unsigned short f2bf(float v) {
  __hip_bfloat16 h = __float2bfloat16(v);
  union { __hip_bfloat16 h; unsigned short u; } cvt; cvt.h = h;
  return cvt.u;
}

// ---------------- K0: pack recurrence weights into MFMA B-fragment order ----------------
// Fragment f = nt*16 + kt. Element (f, lane l, e): k = kt*32 + (l>>4)*8 + e ; n = nt*16 + (l&15).
__global__ __launch_bounds__(256) void pack_weights(const float* __restrict__ Wur,
                                                    const float* __restrict__ U,
                                                    unsigned short* __restrict__ WrPK,
                                                    unsigned short* __restrict__ UPK) {
  int idx = blockIdx.x * 256 + threadIdx.x;    // 512*512 = 262144 total
  int l = idx & 63;
  int e = (idx >> 6) & 7;
  int f = idx >> 9;
  int kt = f & 15, nt = f >> 4;
  int k = kt * 32 + ((l >> 4) << 3) + e;
  int n = (nt << 4) + (l & 15);
  int o = ((f * 64 + l) << 3) + e;
  WrPK[o] = f2bf(Wur[k * 1024 + 512 + n]);
  UPK[o]  = f2bf(U[k * 512 + n]);
}

// ---------------- K1: alpha = inp@Wa+ba (log domain), beta, kinc ----------------
#define ABK_ROWS 8
__global__ __launch_bounds__(64) void abk_kernel(const float* __restrict__ inp,
                                                 const float* __restrict__ Wa, const float* __restrict__ ba,
                                                 const float* __restrict__ Wb, const float* __restrict__ bb_,
                                                 const float* __restrict__ Wk, const float* __restrict__ bk,
                                                 float* __restrict__ alpha, float* __restrict__ beta,
                                                 float* __restrict__ kinc) {
  __shared__ float rows[ABK_ROWS][D];
  int tb0 = blockIdx.x * ABK_ROWS;
  for (int x = threadIdx.x; x < ABK_ROWS * D; x += 64)
    rows[x >> 9][x & 511] = inp[(size_t)tb0 * D + x];
  __syncthreads();
  int j = threadIdx.x;
  if (j >= 3 * KMIX) return;
  int wj = j % KMIX;
  int which = j / KMIX;
  const float* W = (which == 0) ? Wa : ((which == 1) ? Wb : Wk);
  const float* B = (which == 0) ? ba : ((which == 1) ? bb_ : bk);
  float acc[ABK_ROWS];
  float bias = B[wj];
#pragma unroll
  for (int r = 0; r < ABK_ROWS; r++) acc[r] = bias;
  for (int i = 0; i < D; i++) {
    float wv = W[i * KMIX + wj];
#pragma unroll
    for (int r = 0; r < ABK_ROWS; r++) acc[r] += rows[r][i] * wv;
  }
  for (int r = 0; r < ABK_ROWS; r++) {
    int tb = tb0 + r;
    float v = acc[r];
    if (which == 0) alpha[tb * KMIX + wj] = v;
    else if (which == 1) beta[tb * KMIX + wj] = expf(v);
    else kinc[tb * KMIX + wj] = expf(v);
  }
}

// ---------------- K2: k cumsum over t; writes att_k region of d_out ----------------
__global__ __launch_bounds__(256) void cumsum_kernel(const float* __restrict__ att_init,
                                                     const float* __restrict__ kinc,
                                                     float* __restrict__ kout) {
  int idx = blockIdx.x * 256 + threadIdx.x;
  if (idx >= MB * KMIX) return;
  float k = att_init[idx];
  for (int t = 0; t < TS; t++) {
    k += kinc[t * MB * KMIX + idx];
    kout[t * MB * KMIX + idx] = k;
  }
}

// ---------------- K3: phi + w GEMM; writes att_w region of d_out ----------------
#define WT 16
__global__ __launch_bounds__(512) void phi_w_kernel(const float* __restrict__ c_inp,
                                                    const float* __restrict__ alpha,
                                                    const float* __restrict__ beta,
                                                    const float* __restrict__ katt,
                                                    float* __restrict__ wout) {
  int b  = blockIdx.x / (TS / WT);
  int t0 = (blockIdx.x % (TS / WT)) * WT;
  __shared__ float phi[WT][CTS];
  __shared__ float pa[WT][KMIX], pb[WT][KMIX], pk[WT][KMIX];
  for (int x = threadIdx.x; x < WT * KMIX; x += 512) {
    int tt = x / KMIX, j = x % KMIX;
    int tb = (t0 + tt) * MB + b;
    pa[tt][j] = alpha[tb * KMIX + j];
    pb[tt][j] = beta[tb * KMIX + j];
    pk[tt][j] = katt[tb * KMIX + j];
  }
  __syncthreads();
  {
    int c = threadIdx.x;
    float fc = (float)c;
#pragma unroll
    for (int tt = 0; tt < WT; tt++) {
      float s = 0.f;
#pragma unroll
      for (int j = 0; j < KMIX; j++) {
        float dd = pk[tt][j] - fc;
        s += expf(pa[tt][j] - pb[tt][j] * dd * dd);
      }
      phi[tt][c] = s;
    }
  }
  __syncthreads();
  {
    int d = threadIdx.x;
    float acc[WT];
#pragma unroll
    for (int tt = 0; tt < WT; tt++) acc[tt] = 0.f;
    const float* cb = c_inp + (size_t)b * D + d;
    for (int c2 = 0; c2 < CTS; c2++) {
      float cv = cb[(size_t)c2 * (MB * D)];
#pragma unroll
      for (int tt = 0; tt < WT; tt++) acc[tt] += phi[tt][c2] * cv;
    }
    for (int tt = 0; tt < WT; tt++)
      wout[((size_t)(t0 + tt) * MB + b) * D + d] = acc[tt];
  }
}

// ---------------- K4/K5: fp32 tiled GEMM, 128x128 tile ----------------
__global__ __launch_bounds__(256) void gemm128(const float* __restrict__ A,
                                               const float* __restrict__ B,
                                               const float* __restrict__ bias,
                                               const float* __restrict__ wadd,
                                               float* __restrict__ C,
                                               int Kdim, int ldb, int Nout, int remapHalf) {
  __shared__ float As[8][128];
  __shared__ float Bs[8][128];
  const int bm = blockIdx.x, bn = blockIdx.y;
  const int tid = threadIdx.x;
  const int tm = (tid >> 4) << 3;
  const int tn = (tid & 15) << 3;
  const int colOff = (remapHalf && bn >= 4) ? 512 : 0;
  const int n0 = bn * 128;
  float acc[8][8];
#pragma unroll
  for (int i = 0; i < 8; i++)
#pragma unroll
    for (int j = 0; j < 8; j++) acc[i][j] = 0.f;
  const int ar = tid >> 1;
  const int ak = (tid & 1) << 2;
  const int bkr = tid >> 5;
  const int bc = (tid & 31) << 2;
  const float* Aptr = A + (size_t)(bm * 128 + ar) * Kdim + ak;
  const float* Bptr = B + (size_t)bkr * ldb + n0 + colOff + bc;
  for (int k0 = 0; k0 < Kdim; k0 += 8) {
    float4 a4 = *(const float4*)(Aptr + k0);
    float4 b4 = *(const float4*)(Bptr + (size_t)k0 * ldb);
    As[ak + 0][ar] = a4.x; As[ak + 1][ar] = a4.y; As[ak + 2][ar] = a4.z; As[ak + 3][ar] = a4.w;
    *(float4*)&Bs[bkr][bc] = b4;
    __syncthreads();
#pragma unroll
    for (int kk = 0; kk < 8; kk++) {
      float a8[8], b8[8];
      *(float4*)&a8[0] = *(const float4*)&As[kk][tm];
      *(float4*)&a8[4] = *(const float4*)&As[kk][tm + 4];
      *(float4*)&b8[0] = *(const float4*)&Bs[kk][tn];
      *(float4*)&b8[4] = *(const float4*)&Bs[kk][tn + 4];
#pragma unroll
      for (int i = 0; i < 8; i++)
#pragma unroll
        for (int j = 0; j < 8; j++) acc[i][j] += a8[i] * b8[j];
    }
    __syncthreads();
  }
  float bb8[8];
#pragma unroll
  for (int j = 0; j < 8; j++) bb8[j] = bias[n0 + colOff + tn + j];
#pragma unroll
  for (int i = 0; i < 8; i++) {
    int m = bm * 128 + tm + i;
    size_t co = (size_t)m * Nout + n0 + tn;
    float v[8];
#pragma unroll
    for (int j = 0; j < 8; j++) v[j] = acc[i][j] + bb8[j];
    if (wadd) {
      float4 w0 = *(const float4*)&wadd[co];
      float4 w1 = *(const float4*)&wadd[co + 4];
      v[0] += w0.x; v[1] += w0.y; v[2] += w0.z; v[3] += w0.w;
      v[4] += w1.x; v[5] += w1.y; v[6] += w1.z; v[7] += w1.w;
    }
    *(float4*)&C[co]     = make_float4(v[0], v[1], v[2], v[3]);
    *(float4*)&C[co + 4] = make_float4(v[4], v[5], v[6], v[7]);
  }
}

// ---------------- K6: register-resident column-split recurrence ----------------
// 4 blocks x 512 threads (8 waves). Block blk owns output cols [blk*128, blk*128+128).
// Wave w owns global n-tile ntg = blk*8+w; holds Wr/U fragment slices in VGPRs
// (16+16 bf16x8 = 128 VGPR) — loaded ONCE. Per step only h/sr (64KB bf16) is
// exchanged via global workspace + device-scope barrier.
// A-staging LDS buffer abf (64KB) time-shared: h for matvec1, sr for matvec2.
// Frag layout elem offset for value (m, j): [kt=j>>5][m][g'=( (j>>3)&3 )^((m>>2)&3)][e=j&7].

__device__ __forceinline__ int aoff(int m, int j) {
  return ((j >> 5) << 11) + (m << 5) + (((((j >> 3) & 3)) ^ ((m >> 2) & 3)) << 3) + (j & 7);
}

__device__ __forceinline__ float fast_sigmoid(float x) {
  return __builtin_amdgcn_rcpf(1.f + __expf(-x));
}
__device__ __forceinline__ float fast_tanh(float x) {
  x = fminf(15.f, fmaxf(-15.f, x));
  float e = __expf(2.f * x);
  return 1.f - 2.f * __builtin_amdgcn_rcpf(e + 1.f);
}

#define RNB 4
#define RNT 512

__device__ __forceinline__ void gbar(unsigned* bar, int idx) {
  __syncthreads();
  if (threadIdx.x == 0) {
    __threadfence();   // agent release: flush block's writes device-wide
    __hip_atomic_fetch_add(bar + idx, 1u, __ATOMIC_RELEASE, __HIP_MEMORY_SCOPE_AGENT);
    while (__hip_atomic_load(bar + idx, __ATOMIC_ACQUIRE, __HIP_MEMORY_SCOPE_AGENT) < (unsigned)RNB) {
      __builtin_amdgcn_s_sleep(1);
    }
    __threadfence();   // agent acquire: invalidate stale caches
  }
  __syncthreads();
}

__global__ __launch_bounds__(RNT, 2) void recurrence_split(
    const float* __restrict__ F2,
    const bf16x8* __restrict__ WrPK,
    const bf16x8* __restrict__ UPK,
    const float* __restrict__ gru_init,
    float* __restrict__ hout,
    unsigned short* __restrict__ SRX,
    unsigned short* __restrict__ HX,
    unsigned* __restrict__ bar) {
  __shared__ unsigned short abf[64 * 512];   // 64KB
  const int tid  = threadIdx.x;
  const int wave = tid >> 6;
  const int lane = tid & 63;
  const int lg = lane >> 4;
  const int ln = lane & 15;
  const int blk = blockIdx.x;
  const int ntg = blk * 8 + wave;
  const int jcol = ntg * 16 + ln;

  // ---- resident weight slices (static indices; stays in VGPRs) ----
  bf16x8 wrw[16], uw[16];
#pragma unroll
  for (int kt = 0; kt < 16; kt++) {
    wrw[kt] = WrPK[((ntg * 16 + kt) << 6) + lane];
    uw[kt]  = UPK[((ntg * 16 + kt) << 6) + lane];
  }

  // ---- init: full h0 into abf; wave's h master into regs ----
  for (int idx = tid; idx < 64 * 512; idx += RNT) {
    int m = idx >> 9, j = idx & 511;
    abf[aoff(m, j)] = f2bf(gru_init[idx]);
  }
  float hreg[4][4];
#pragma unroll
  for (int mt = 0; mt < 4; mt++)
#pragma unroll
    for (int r = 0; r < 4; r++)
      hreg[mt][r] = gru_init[(mt * 16 + lg * 4 + r) * D + jcol];
  __syncthreads();

  const f32x4 zero4 = {0.f, 0.f, 0.f, 0.f};
#pragma unroll 1
  for (int t = 0; t < TS; t++) {
    // F2 loads for this step (consumed after matvec1 — latency hidden)
    const float* f2 = F2 + (size_t)t * (MB * 1024);
    float sreg[4][4], greg[4][4];
#pragma unroll
    for (int mt = 0; mt < 4; mt++)
#pragma unroll
      for (int r = 0; r < 4; r++) {
        int m = mt * 16 + lg * 4 + r;
        sreg[mt][r] = f2[m * 1024 + jcol];
        greg[mt][r] = f2[m * 1024 + 512 + jcol];
      }
    // ---- matvec1: c1 = h @ Wr[:, wave cols] over all 64 batches ----
    f32x4 c1[4] = {zero4, zero4, zero4, zero4};
#pragma unroll
    for (int kt = 0; kt < 16; kt++) {
#pragma unroll
      for (int mt = 0; mt < 4; mt++) {
        int m = mt * 16 + ln;
        bf16x8 a = *(const bf16x8*)(abf + (kt << 11) + (m << 5) + ((lg ^ ((m >> 2) & 3)) << 3));
        c1[mt] = __builtin_amdgcn_mfma_f32_16x16x32_bf16(a, wrw[kt], c1[mt], 0, 0, 0);
      }
    }
    __syncthreads();           // everyone done reading h from abf
    // ---- epilogue1: sr = s * sigmoid(c1 + g) into abf (own cols) ----
#pragma unroll
    for (int mt = 0; mt < 4; mt++)
#pragma unroll
      for (int r = 0; r < 4; r++) {
        int m = mt * 16 + lg * 4 + r;
        float rr = fast_sigmoid(c1[mt][r] + greg[mt][r]);
        abf[aoff(m, jcol)] = f2bf(sreg[mt][r] * rr);
      }
    __syncthreads();
    // ---- exchange sr: copy own 16KB slice out, barrier, pull others' 48KB ----
    {
      const uint4* src = (const uint4*)abf;
      uint4* dst = (uint4*)SRX;
#pragma unroll
      for (int c = 0; c < 2; c++)
        dst[(blk << 10) + tid + c * RNT] = src[(blk << 10) + tid + c * RNT];
    }
    gbar(bar, 2 * t);
    {
      const uint4* src = (const uint4*)SRX;
      uint4* dst = (uint4*)abf;
#pragma unroll
      for (int c = 0; c < 8; c++) {
        int idx = tid + c * RNT;
        if ((idx >> 10) != blk) dst[idx] = src[idx];
      }
    }
    __syncthreads();
    // ---- matvec2: c2 = sr @ U[:, wave cols] ----
    f32x4 c2[4] = {zero4, zero4, zero4, zero4};
#pragma unroll
    for (int kt = 0; kt < 16; kt++) {
#pragma unroll
      for (int mt = 0; mt < 4; mt++) {
        int m = mt * 16 + ln;
        bf16x8 a = *(const bf16x8*)(abf + (kt << 11) + (m << 5) + ((lg ^ ((m >> 2) & 3)) << 3));
        c2[mt] = __builtin_amdgcn_mfma_f32_16x16x32_bf16(a, uw[kt], c2[mt], 0, 0, 0);
      }
    }
    __syncthreads();           // everyone done reading sr from abf
    // ---- epilogue2: h' = h + 1 + tanh(c2 + s); write hout + abf ----
#pragma unroll
    for (int mt = 0; mt < 4; mt++)
#pragma unroll
      for (int r = 0; r < 4; r++) {
        int m = mt * 16 + lg * 4 + r;
        float hn = hreg[mt][r] + 1.f + fast_tanh(c2[mt][r] + sreg[mt][r]);
        hreg[mt][r] = hn;
        hout[((size_t)t * MB + m) * D + jcol] = hn;
        abf[aoff(m, jcol)] = f2bf(hn);
      }
    __syncthreads();
    // ---- exchange h': copy own slice out, barrier, pull others' ----
    {
      const uint4* src = (const uint4*)abf;
      uint4* dst = (uint4*)HX;
#pragma unroll
      for (int c = 0; c < 2; c++)
        dst[(blk << 10) + tid + c * RNT] = src[(blk << 10) + tid + c * RNT];
    }
    gbar(bar, 2 * t + 1);
    {
      const uint4* src = (const uint4*)HX;
      uint4* dst = (uint4*)abf;
#pragma unroll
      for (int c = 0; c < 8; c++) {
        int idx = tid + c * RNT;
        if ((idx >> 10) != blk) dst[idx] = src[idx];
      }
    }
    __syncthreads();
  }
}

extern "C" void kernel_launch(void* const* d_in, const int* in_sizes, int n_in,
                              void* d_out, int out_size, void* d_ws, size_t ws_size,
                              hipStream_t stream) {
  const float* c_inp    = (const float*)d_in[0];
  const float* inp      = (const float*)d_in[1];
  const float* gru_init = (const float*)d_in[2];
  const float* att_init = (const float*)d_in[3];
  const float* Wa   = (const float*)d_in[4];
  const float* ba   = (const float*)d_in[5];
  const float* Wb   = (const float*)d_in[6];
  const float* bb   = (const float*)d_in[7];
  const float* Wk   = (const float*)d_in[8];
  const float* bk   = (const float*)d_in[9];
  const float* Wif  = (const float*)d_in[10];
  const float* bif  = (const float*)d_in[11];
  const float* Wfork= (const float*)d_in[12];
  const float* bfork= (const float*)d_in[13];
  const float* Wur  = (const float*)d_in[14];
  const float* U    = (const float*)d_in[15];

  float* out = (float*)d_out;
  float* hid  = out;
  float* attk = out + ATTK_OFF;
  float* attw = out + ATTW_OFF;

  char* ws = (char*)d_ws;
  unsigned short* WrPK = (unsigned short*)(ws + WS_WRPK);
  unsigned short* UPK  = (unsigned short*)(ws + WS_UPK);
  float* alpha = (float*)(ws + WS_ALPHA);
  float* beta  = (float*)(ws + WS_BETA);
  float* kinc  = (float*)(ws + WS_KINC);
  unsigned* bar        = (unsigned*)(ws + WS_BAR);
  unsigned short* SRX  = (unsigned short*)(ws + WS_SRX);
  unsigned short* HX   = (unsigned short*)(ws + WS_HX);
  float* X     = (float*)(ws + WS_X);
  float* F2    = (float*)(ws + WS_F2);

  hipMemsetAsync(bar, 0, 4096, stream);   // zero barrier counters every launch
  hipLaunchKernelGGL(pack_weights, dim3(1024), dim3(256), 0, stream, Wur, U, WrPK, UPK);
  hipLaunchKernelGGL(abk_kernel, dim3(TS * MB / ABK_ROWS), dim3(64), 0, stream,
                     inp, Wa, ba, Wb, bb, Wk, bk, alpha, beta, kinc);
  hipLaunchKernelGGL(cumsum_kernel, dim3((MB * KMIX + 255) / 256), dim3(256), 0, stream,
                     att_init, kinc, attk);
  hipLaunchKernelGGL(phi_w_kernel, dim3(MB * (TS / WT)), dim3(512), 0, stream,
                     c_inp, alpha, beta, attk, attw);
  hipLaunchKernelGGL(gemm128, dim3(TS * MB / 128, D / 128), dim3(256), 0, stream,
                     inp, Wif, bif, attw, X, D, D, D, 0);
  hipLaunchKernelGGL(gemm128, dim3(TS * MB / 128, 1024 / 128), dim3(256), 0, stream,
                     X, Wfork, bfork, (const float*)nullptr, F2, D, 3 * D, 1024, 1);
  hipLaunchKernelGGL(recurrence_split, dim3(RNB), dim3(RNT), 0, stream,
                     F2, (const bf16x8*)WrPK, (const bf16x8*)UPK, gru_init, hid, SRX, HX, bar);
}

// Round 7
// 5806.589 us; speedup vs baseline: 1.2195x; 1.0328x over previous
//
#include <hip/hip_runtime.h>
#include <hip/hip_bf16.h>
#include <math.h>

#define TS   256
#define CTS  512
#define MB   64
#define D    512
#define KMIX 20

// d_out layout (floats): hiddens [TS][MB][D], att_k [TS][MB][KMIX], att_w [TS][MB][D]
#define HID_SIZE  (TS*MB*D)
#define ATTK_OFF  (HID_SIZE)
#define ATTW_OFF  (HID_SIZE + TS*MB*KMIX)

// ws layout (bytes):
#define WS_WRPK  0
#define WS_UPK   524288
#define WS_ALPHA 1048576
#define WS_BETA  2359296
#define WS_KINC  3670016
// gap 4980736..5242880 reused for barrier + exchange buffers:
#define WS_BAR   4980736      // 4KB (512 u32 counters used)
#define WS_SRX   4984832      // 64KB bf16 sr exchange (frag layout)
#define WS_HX    5050368      // 64KB bf16 h  exchange (frag layout)
#define WS_X     5242880
#define WS_F2    38797312

typedef __attribute__((ext_vector_type(8))) short bf16x8;
typedef __attribute__((ext_vector_type(4))) float f32x4;

__device__ __forceinline__ unsigned short f2bf(float v) {
  __hip_bfloat16 h = __float2bfloat16(v);
  union { __hip_bfloat16 h; unsigned short u; } cvt; cvt.h = h;
  return cvt.u;
}

// ---------------- K0: pack recurrence weights into MFMA B-fragment order ----------------
// Fragment f = nt*16 + kt. Element (f, lane l, e): k = kt*32 + (l>>4)*8 + e ; n = nt*16 + (l&15).
__global__ __launch_bounds__(256) void pack_weights(const float* __restrict__ Wur,
                                                    const float* __restrict__ U,
                                                    unsigned short* __restrict__ WrPK,
                                                    unsigned short* __restrict__ UPK) {
  int idx = blockIdx.x * 256 + threadIdx.x;    // 512*512 = 262144 total
  int l = idx & 63;
  int e = (idx >> 6) & 7;
  int f = idx >> 9;
  int kt = f & 15, nt = f >> 4;
  int k = kt * 32 + ((l >> 4) << 3) + e;
  int n = (nt << 4) + (l & 15);
  int o = ((f * 64 + l) << 3) + e;
  WrPK[o] = f2bf(Wur[k * 1024 + 512 + n]);
  UPK[o]  = f2bf(U[k * 512 + n]);
}

// ---------------- K1: alpha = inp@Wa+ba (log domain), beta, kinc ----------------
#define ABK_ROWS 8
__global__ __launch_bounds__(64) void abk_kernel(const float* __restrict__ inp,
                                                 const float* __restrict__ Wa, const float* __restrict__ ba,
                                                 const float* __restrict__ Wb, const float* __restrict__ bb_,
                                                 const float* __restrict__ Wk, const float* __restrict__ bk,
                                                 float* __restrict__ alpha, float* __restrict__ beta,
                                                 float* __restrict__ kinc) {
  __shared__ float rows[ABK_ROWS][D];
  int tb0 = blockIdx.x * ABK_ROWS;
  for (int x = threadIdx.x; x < ABK_ROWS * D; x += 64)
    rows[x >> 9][x & 511] = inp[(size_t)tb0 * D + x];
  __syncthreads();
  int j = threadIdx.x;
  if (j >= 3 * KMIX) return;
  int wj = j % KMIX;
  int which = j / KMIX;
  const float* W = (which == 0) ? Wa : ((which == 1) ? Wb : Wk);
  const float* B = (which == 0) ? ba : ((which == 1) ? bb_ : bk);
  float acc[ABK_ROWS];
  float bias = B[wj];
#pragma unroll
  for (int r = 0; r < ABK_ROWS; r++) acc[r] = bias;
  for (int i = 0; i < D; i++) {
    float wv = W[i * KMIX + wj];
#pragma unroll
    for (int r = 0; r < ABK_ROWS; r++) acc[r] += rows[r][i] * wv;
  }
  for (int r = 0; r < ABK_ROWS; r++) {
    int tb = tb0 + r;
    float v = acc[r];
    if (which == 0) alpha[tb * KMIX + wj] = v;
    else if (which == 1) beta[tb * KMIX + wj] = expf(v);
    else kinc[tb * KMIX + wj] = expf(v);
  }
}

// ---------------- K2: k cumsum over t; writes att_k region of d_out ----------------
__global__ __launch_bounds__(256) void cumsum_kernel(const float* __restrict__ att_init,
                                                     const float* __restrict__ kinc,
                                                     float* __restrict__ kout) {
  int idx = blockIdx.x * 256 + threadIdx.x;
  if (idx >= MB * KMIX) return;
  float k = att_init[idx];
  for (int t = 0; t < TS; t++) {
    k += kinc[t * MB * KMIX + idx];
    kout[t * MB * KMIX + idx] = k;
  }
}

// ---------------- K3: phi + w GEMM; writes att_w region of d_out ----------------
#define WT 16
__global__ __launch_bounds__(512) void phi_w_kernel(const float* __restrict__ c_inp,
                                                    const float* __restrict__ alpha,
                                                    const float* __restrict__ beta,
                                                    const float* __restrict__ katt,
                                                    float* __restrict__ wout) {
  int b  = blockIdx.x / (TS / WT);
  int t0 = (blockIdx.x % (TS / WT)) * WT;
  __shared__ float phi[WT][CTS];
  __shared__ float pa[WT][KMIX], pb[WT][KMIX], pk[WT][KMIX];
  for (int x = threadIdx.x; x < WT * KMIX; x += 512) {
    int tt = x / KMIX, j = x % KMIX;
    int tb = (t0 + tt) * MB + b;
    pa[tt][j] = alpha[tb * KMIX + j];
    pb[tt][j] = beta[tb * KMIX + j];
    pk[tt][j] = katt[tb * KMIX + j];
  }
  __syncthreads();
  {
    int c = threadIdx.x;
    float fc = (float)c;
#pragma unroll
    for (int tt = 0; tt < WT; tt++) {
      float s = 0.f;
#pragma unroll
      for (int j = 0; j < KMIX; j++) {
        float dd = pk[tt][j] - fc;
        s += expf(pa[tt][j] - pb[tt][j] * dd * dd);
      }
      phi[tt][c] = s;
    }
  }
  __syncthreads();
  {
    int d = threadIdx.x;
    float acc[WT];
#pragma unroll
    for (int tt = 0; tt < WT; tt++) acc[tt] = 0.f;
    const float* cb = c_inp + (size_t)b * D + d;
    for (int c2 = 0; c2 < CTS; c2++) {
      float cv = cb[(size_t)c2 * (MB * D)];
#pragma unroll
      for (int tt = 0; tt < WT; tt++) acc[tt] += phi[tt][c2] * cv;
    }
    for (int tt = 0; tt < WT; tt++)
      wout[((size_t)(t0 + tt) * MB + b) * D + d] = acc[tt];
  }
}

// ---------------- K4/K5: fp32 tiled GEMM, 128x128 tile ----------------
__global__ __launch_bounds__(256) void gemm128(const float* __restrict__ A,
                                               const float* __restrict__ B,
                                               const float* __restrict__ bias,
                                               const float* __restrict__ wadd,
                                               float* __restrict__ C,
                                               int Kdim, int ldb, int Nout, int remapHalf) {
  __shared__ float As[8][128];
  __shared__ float Bs[8][128];
  const int bm = blockIdx.x, bn = blockIdx.y;
  const int tid = threadIdx.x;
  const int tm = (tid >> 4) << 3;
  const int tn = (tid & 15) << 3;
  const int colOff = (remapHalf && bn >= 4) ? 512 : 0;
  const int n0 = bn * 128;
  float acc[8][8];
#pragma unroll
  for (int i = 0; i < 8; i++)
#pragma unroll
    for (int j = 0; j < 8; j++) acc[i][j] = 0.f;
  const int ar = tid >> 1;
  const int ak = (tid & 1) << 2;
  const int bkr = tid >> 5;
  const int bc = (tid & 31) << 2;
  const float* Aptr = A + (size_t)(bm * 128 + ar) * Kdim + ak;
  const float* Bptr = B + (size_t)bkr * ldb + n0 + colOff + bc;
  for (int k0 = 0; k0 < Kdim; k0 += 8) {
    float4 a4 = *(const float4*)(Aptr + k0);
    float4 b4 = *(const float4*)(Bptr + (size_t)k0 * ldb);
    As[ak + 0][ar] = a4.x; As[ak + 1][ar] = a4.y; As[ak + 2][ar] = a4.z; As[ak + 3][ar] = a4.w;
    *(float4*)&Bs[bkr][bc] = b4;
    __syncthreads();
#pragma unroll
    for (int kk = 0; kk < 8; kk++) {
      float a8[8], b8[8];
      *(float4*)&a8[0] = *(const float4*)&As[kk][tm];
      *(float4*)&a8[4] = *(const float4*)&As[kk][tm + 4];
      *(float4*)&b8[0] = *(const float4*)&Bs[kk][tn];
      *(float4*)&b8[4] = *(const float4*)&Bs[kk][tn + 4];
#pragma unroll
      for (int i = 0; i < 8; i++)
#pragma unroll
        for (int j = 0; j < 8; j++) acc[i][j] += a8[i] * b8[j];
    }
    __syncthreads();
  }
  float bb8[8];
#pragma unroll
  for (int j = 0; j < 8; j++) bb8[j] = bias[n0 + colOff + tn + j];
#pragma unroll
  for (int i = 0; i < 8; i++) {
    int m = bm * 128 + tm + i;
    size_t co = (size_t)m * Nout + n0 + tn;
    float v[8];
#pragma unroll
    for (int j = 0; j < 8; j++) v[j] = acc[i][j] + bb8[j];
    if (wadd) {
      float4 w0 = *(const float4*)&wadd[co];
      float4 w1 = *(const float4*)&wadd[co + 4];
      v[0] += w0.x; v[1] += w0.y; v[2] += w0.z; v[3] += w0.w;
      v[4] += w1.x; v[5] += w1.y; v[6] += w1.z; v[7] += w1.w;
    }
    *(float4*)&C[co]     = make_float4(v[0], v[1], v[2], v[3]);
    *(float4*)&C[co + 4] = make_float4(v[4], v[5], v[6], v[7]);
  }
}

// ---------------- K6: register-resident column-split recurrence ----------------
// 4 blocks x 512 threads (8 waves). Block blk owns output cols [blk*128, blk*128+128).
// Wave w owns global n-tile ntg = blk*8+w; holds Wr/U fragment slices in VGPRs
// (16+16 bf16x8 = 128 VGPR) — loaded ONCE, PINNED via keep-alive asm so the
// compiler cannot rematerialize the loads (round-6 lesson: it did, VGPR=64/128).
// Per step only h/sr (64KB bf16) is exchanged via workspace + device barrier.
// A-staging LDS buffer abf (64KB) time-shared: h for matvec1, sr for matvec2.

__device__ __forceinline__ int aoff(int m, int j) {
  return ((j >> 5) << 11) + (m << 5) + (((((j >> 3) & 3)) ^ ((m >> 2) & 3)) << 3) + (j & 7);
}

__device__ __forceinline__ float fast_sigmoid(float x) {
  return __builtin_amdgcn_rcpf(1.f + __expf(-x));
}
__device__ __forceinline__ float fast_tanh(float x) {
  x = fminf(15.f, fmaxf(-15.f, x));
  float e = __expf(2.f * x);
  return 1.f - 2.f * __builtin_amdgcn_rcpf(e + 1.f);
}

#define RNB 4
#define RNT 512

__device__ __forceinline__ void gbar(unsigned* bar, int idx) {
  __syncthreads();
  if (threadIdx.x == 0) {
    __threadfence();   // agent release: flush block's writes device-wide
    __hip_atomic_fetch_add(bar + idx, 1u, __ATOMIC_RELEASE, __HIP_MEMORY_SCOPE_AGENT);
    while (__hip_atomic_load(bar + idx, __ATOMIC_ACQUIRE, __HIP_MEMORY_SCOPE_AGENT) < (unsigned)RNB) {
      __builtin_amdgcn_s_sleep(1);
    }
    __threadfence();   // agent acquire: invalidate stale caches
  }
  __syncthreads();
}

__global__ __launch_bounds__(RNT, 2) void recurrence_split(
    const float* __restrict__ F2,
    const bf16x8* __restrict__ WrPK,
    const bf16x8* __restrict__ UPK,
    const float* __restrict__ gru_init,
    float* __restrict__ hout,
    unsigned short* __restrict__ SRX,
    unsigned short* __restrict__ HX,
    unsigned* __restrict__ bar) {
  __shared__ unsigned short abf[64 * 512];   // 64KB
  const int tid  = threadIdx.x;
  const int wave = tid >> 6;
  const int lane = tid & 63;
  const int lg = lane >> 4;
  const int ln = lane & 15;
  const int blk = blockIdx.x;
  const int ntg = blk * 8 + wave;
  const int jcol = ntg * 16 + ln;

  // ---- resident weight slices: load once, then PIN with keep-alive asm ----
  bf16x8 wrw[16], uw[16];
#pragma unroll
  for (int kt = 0; kt < 16; kt++) {
    wrw[kt] = WrPK[((ntg * 16 + kt) << 6) + lane];
    uw[kt]  = UPK[((ntg * 16 + kt) << 6) + lane];
  }
#pragma unroll
  for (int kt = 0; kt < 16; kt++) {
    asm volatile("" : "+v"(wrw[kt]));
    asm volatile("" : "+v"(uw[kt]));
  }

  // ---- init: full h0 into abf; wave's h master into regs ----
  for (int idx = tid; idx < 64 * 512; idx += RNT) {
    int m = idx >> 9, j = idx & 511;
    abf[aoff(m, j)] = f2bf(gru_init[idx]);
  }
  float hreg[4][4];
#pragma unroll
  for (int mt = 0; mt < 4; mt++)
#pragma unroll
    for (int r = 0; r < 4; r++)
      hreg[mt][r] = gru_init[(mt * 16 + lg * 4 + r) * D + jcol];
  __syncthreads();

  const f32x4 zero4 = {0.f, 0.f, 0.f, 0.f};
#pragma unroll 1
  for (int t = 0; t < TS; t++) {
    // F2 loads for this step (consumed after matvec1 — latency hidden)
    const float* f2 = F2 + (size_t)t * (MB * 1024);
    float sreg[4][4], greg[4][4];
#pragma unroll
    for (int mt = 0; mt < 4; mt++)
#pragma unroll
      for (int r = 0; r < 4; r++) {
        int m = mt * 16 + lg * 4 + r;
        sreg[mt][r] = f2[m * 1024 + jcol];
        greg[mt][r] = f2[m * 1024 + 512 + jcol];
      }
    // ---- matvec1: c1 = h @ Wr[:, wave cols] over all 64 batches ----
    f32x4 c1[4] = {zero4, zero4, zero4, zero4};
#pragma unroll
    for (int kt = 0; kt < 16; kt++) {
#pragma unroll
      for (int mt = 0; mt < 4; mt++) {
        int m = mt * 16 + ln;
        bf16x8 a = *(const bf16x8*)(abf + (kt << 11) + (m << 5) + ((lg ^ ((m >> 2) & 3)) << 3));
        c1[mt] = __builtin_amdgcn_mfma_f32_16x16x32_bf16(a, wrw[kt], c1[mt], 0, 0, 0);
      }
    }
    __syncthreads();           // everyone done reading h from abf
    // ---- epilogue1: sr = s * sigmoid(c1 + g) into abf (own cols) ----
#pragma unroll
    for (int mt = 0; mt < 4; mt++)
#pragma unroll
      for (int r = 0; r < 4; r++) {
        int m = mt * 16 + lg * 4 + r;
        float rr = fast_sigmoid(c1[mt][r] + greg[mt][r]);
        abf[aoff(m, jcol)] = f2bf(sreg[mt][r] * rr);
      }
    __syncthreads();
    // ---- exchange sr: copy own 16KB slice out, barrier, pull others' 48KB ----
    {
      const uint4* src = (const uint4*)abf;
      uint4* dst = (uint4*)SRX;
#pragma unroll
      for (int c = 0; c < 2; c++)
        dst[(blk << 10) + tid + c * RNT] = src[(blk << 10) + tid + c * RNT];
    }
    gbar(bar, 2 * t);
    {
      const uint4* src = (const uint4*)SRX;
      uint4* dst = (uint4*)abf;
#pragma unroll
      for (int c = 0; c < 8; c++) {
        int idx = tid + c * RNT;
        if ((idx >> 10) != blk) dst[idx] = src[idx];
      }
    }
    __syncthreads();
    // ---- matvec2: c2 = sr @ U[:, wave cols] ----
    f32x4 c2[4] = {zero4, zero4, zero4, zero4};
#pragma unroll
    for (int kt = 0; kt < 16; kt++) {
#pragma unroll
      for (int mt = 0; mt < 4; mt++) {
        int m = mt * 16 + ln;
        bf16x8 a = *(const bf16x8*)(abf + (kt << 11) + (m << 5) + ((lg ^ ((m >> 2) & 3)) << 3));
        c2[mt] = __builtin_amdgcn_mfma_f32_16x16x32_bf16(a, uw[kt], c2[mt], 0, 0, 0);
      }
    }
    __syncthreads();           // everyone done reading sr from abf
    // ---- epilogue2: h' = h + 1 + tanh(c2 + s); write hout + abf ----
#pragma unroll
    for (int mt = 0; mt < 4; mt++)
#pragma unroll
      for (int r = 0; r < 4; r++) {
        int m = mt * 16 + lg * 4 + r;
        float hn = hreg[mt][r] + 1.f + fast_tanh(c2[mt][r] + sreg[mt][r]);
        hreg[mt][r] = hn;
        hout[((size_t)t * MB + m) * D + jcol] = hn;
        abf[aoff(m, jcol)] = f2bf(hn);
      }
    __syncthreads();
    // ---- exchange h': copy own slice out, barrier, pull others' ----
    {
      const uint4* src = (const uint4*)abf;
      uint4* dst = (uint4*)HX;
#pragma unroll
      for (int c = 0; c < 2; c++)
        dst[(blk << 10) + tid + c * RNT] = src[(blk << 10) + tid + c * RNT];
    }
    gbar(bar, 2 * t + 1);
    {
      const uint4* src = (const uint4*)HX;
      uint4* dst = (uint4*)abf;
#pragma unroll
      for (int c = 0; c < 8; c++) {
        int idx = tid + c * RNT;
        if ((idx >> 10) != blk) dst[idx] = src[idx];
      }
    }
    __syncthreads();
  }
}

extern "C" void kernel_launch(void* const* d_in, const int* in_sizes, int n_in,
                              void* d_out, int out_size, void* d_ws, size_t ws_size,
                              hipStream_t stream) {
  const float* c_inp    = (const float*)d_in[0];
  const float* inp      = (const float*)d_in[1];
  const float* gru_init = (const float*)d_in[2];
  const float* att_init = (const float*)d_in[3];
  const float* Wa   = (const float*)d_in[4];
  const float* ba   = (const float*)d_in[5];
  const float* Wb   = (const float*)d_in[6];
  const float* bb   = (const float*)d_in[7];
  const float* Wk   = (const float*)d_in[8];
  const float* bk   = (const float*)d_in[9];
  const float* Wif  = (const float*)d_in[10];
  const float* bif  = (const float*)d_in[11];
  const float* Wfork= (const float*)d_in[12];
  const float* bfork= (const float*)d_in[13];
  const float* Wur  = (const float*)d_in[14];
  const float* U    = (const float*)d_in[15];

  float* out = (float*)d_out;
  float* hid  = out;
  float* attk = out + ATTK_OFF;
  float* attw = out + ATTW_OFF;

  char* ws = (char*)d_ws;
  unsigned short* WrPK = (unsigned short*)(ws + WS_WRPK);
  unsigned short* UPK  = (unsigned short*)(ws + WS_UPK);
  float* alpha = (float*)(ws + WS_ALPHA);
  float* beta  = (float*)(ws + WS_BETA);
  float* kinc  = (float*)(ws + WS_KINC);
  unsigned* bar        = (unsigned*)(ws + WS_BAR);
  unsigned short* SRX  = (unsigned short*)(ws + WS_SRX);
  unsigned short* HX   = (unsigned short*)(ws + WS_HX);
  float* X     = (float*)(ws + WS_X);
  float* F2    = (float*)(ws + WS_F2);

  hipMemsetAsync(bar, 0, 4096, stream);   // zero barrier counters every launch
  hipLaunchKernelGGL(pack_weights, dim3(1024), dim3(256), 0, stream, Wur, U, WrPK, UPK);
  hipLaunchKernelGGL(abk_kernel, dim3(TS * MB / ABK_ROWS), dim3(64), 0, stream,
                     inp, Wa, ba, Wb, bb, Wk, bk, alpha, beta, kinc);
  hipLaunchKernelGGL(cumsum_kernel, dim3((MB * KMIX + 255) / 256), dim3(256), 0, stream,
                     att_init, kinc, attk);
  hipLaunchKernelGGL(phi_w_kernel, dim3(MB * (TS / WT)), dim3(512), 0, stream,
                     c_inp, alpha, beta, attk, attw);
  hipLaunchKernelGGL(gemm128, dim3(TS * MB / 128, D / 128), dim3(256), 0, stream,
                     inp, Wif, bif, attw, X, D, D, D, 0);
  hipLaunchKernelGGL(gemm128, dim3(TS * MB / 128, 1024 / 128), dim3(256), 0, stream,
                     X, Wfork, bfork, (const float*)nullptr, F2, D, 3 * D, 1024, 1);
  hipLaunchKernelGGL(recurrence_split, dim3(RNB), dim3(RNT), 0, stream,
                     F2, (const bf16x8*)WrPK, (const bf16x8*)UPK, gru_init, hid, SRX, HX, bar);
}